// Round 6
// baseline (3041.661 us; speedup 1.0000x reference)
//
#include <hip/hip_runtime.h>

#define T_STEPS 1000
#define IN 13
#define HID 32
#define EPB 4            // batch elements per block

// ---------- f64 exp/sigmoid — IDENTICAL numerics to R3/R4/R5 (absmax==0) ----------
__device__ __forceinline__ double exp_d(double u) {
    const double INV_LN2 = 1.4426950408889634074;
    const double LN2_HI  = 6.93147180369123816490e-01;
    const double LN2_LO  = 1.90821492927058770002e-10;
    const double MAGIC   = 6755399441055744.0;          // 1.5 * 2^52
    double s  = fma(u, INV_LN2, MAGIC);
    int    n  = (int)__double2loint(s);
    double nd = s - MAGIC;
    double r  = fma(nd, -LN2_HI, u);
    r = fma(nd, -LN2_LO, r);
    double p = 2.4801587301587301587e-5;
    p = fma(p, r, 1.9841269841269841270e-4);
    p = fma(p, r, 1.3888888888888888889e-3);
    p = fma(p, r, 8.3333333333333333333e-3);
    p = fma(p, r, 4.1666666666666666667e-2);
    p = fma(p, r, 1.6666666666666666667e-1);
    p = fma(p, r, 0.5);
    p = fma(p, r, 1.0);
    p = fma(p, r, 1.0);
    return __hiloint2double(__double2hiint(p) + (n << 20), __double2loint(p));
}

__device__ __forceinline__ double sigmoid_d(double x) {
    double u = fmin(fmax(-x, -30.0), 30.0);
    double e = exp_d(u);
    double d = 1.0 + e;
    double r0 = (double)__builtin_amdgcn_rcpf((float)d);
    return r0 * fma(-d, r0, 2.0);
}

__device__ __forceinline__ double tanh_d(double x) {
    return fma(2.0, sigmoid_d(x + x), -1.0);
}

__device__ __forceinline__ double act_fn(double x, bool istanh) {
    double pre = istanh ? (x + x) : x;
    double sv  = sigmoid_d(pre);
    return istanh ? fma(2.0, sv, -1.0) : sv;
}

// wave-wide broadcast of lane `src`'s double via v_readlane -> SGPR pair
// (feeds v_fma_f64 as its one scalar operand; stays OFF the LDS pipe)
__device__ __forceinline__ double bcast_d(double v, int src) {
    union { double d; int i[2]; } u, r;
    u.d = v;
    r.i[0] = __builtin_amdgcn_readlane(u.i[0], src);
    r.i[1] = __builtin_amdgcn_readlane(u.i[1], src);
    return r.d;
}

__device__ __forceinline__ double shflx32_d(double v) {
    union { double d; int i[2]; } u, r;
    u.d = v;
    r.i[0] = __shfl_xor(u.i[0], 32);
    r.i[1] = __shfl_xor(u.i[1], 32);
    return r.d;
}

// Block = 256 thr = 4 waves, 4 batch elements. Wave roles (rotated by blockIdx for
// SIMD balance): 0: L0 cell-recurrence elems{0,1}; 1: L0 elems{2,3};
// 2: feeder (P_x = Wih0*x+b0 one step ahead; P_ih = b1 + Wih1*h0);
// 3: L1 cell-recurrence (Whh1*h1 + P_ih -> acts -> cells), all 4 elems.
// Each recurrence is WHOLE within one wave (h broadcast from own lanes via
// readlane) -> one barrier/iter, pipeline depth 2 (L1 step s finishes at iter s+2).
__global__ __launch_bounds__(256, 2)
void lstm_fused(const float* __restrict__ X,
                const float* __restrict__ Wih0, const float* __restrict__ Whh0,
                const float* __restrict__ bih0, const float* __restrict__ bhh0,
                const float* __restrict__ Wih1, const float* __restrict__ Whh1,
                const float* __restrict__ bih1, const float* __restrict__ bhh1,
                const float* __restrict__ Wc1,  const float* __restrict__ bc1,
                const float* __restrict__ Wc2,  const float* __restrict__ bc2,
                float* __restrict__ out)
{
    const int tid   = threadIdx.x;
    const int wv    = tid >> 6;
    const int lane  = tid & 63;
    const int role  = (wv + (int)blockIdx.x) & 3;
    const int eA    = blockIdx.x * EPB;
    const int l32   = lane & 31;
    const bool hi32 = (lane >= 32);

    // LDS: handoff-only (no broadcast storms). P layout: [parity][producer-lane][slot]
    // slot = e + 4*rowhalf (producer lane m owns gate-rows m and m+64); +2 pad -> 80B
    // row stride spreads b128 accesses over all 32 banks.
    __shared__ double h0L[2][EPB][HID];
    __shared__ double Px[2][64][10];
    __shared__ double Pi[2][64][10];
    __shared__ double h1F[EPB][HID];
    __shared__ double hidb[HID][EPB];

    // ---- single aliased weight array => union-max register allocation (~180 VGPR) ----
    // role 0/1: [0:32)=Whh0 row lane, [32:64)=Whh0 row lane+64
    // role 3:   same with Whh1
    // role 2:   [0:13)=Wih0 row lane, [13:26)=Wih0 row lane+64,
    //           [26:58)=Wih1 row lane, [58:90)=Wih1 row lane+64
    double wreg[90];
    double b0A = 0., b0B = 0., b1A = 0., b1B = 0.;

    if (role <= 1) {
        #pragma unroll
        for (int j = 0; j < HID; ++j) {
            wreg[j]      = (double)Whh0[lane * HID + j];
            wreg[32 + j] = (double)Whh0[(lane + 64) * HID + j];
        }
    } else if (role == 3) {
        #pragma unroll
        for (int j = 0; j < HID; ++j) {
            wreg[j]      = (double)Whh1[lane * HID + j];
            wreg[32 + j] = (double)Whh1[(lane + 64) * HID + j];
        }
    } else {
        #pragma unroll
        for (int i = 0; i < IN; ++i) {
            wreg[i]      = (double)Wih0[lane * IN + i];
            wreg[13 + i] = (double)Wih0[(lane + 64) * IN + i];
        }
        #pragma unroll
        for (int j = 0; j < HID; ++j) {
            wreg[26 + j] = (double)Wih1[lane * HID + j];
            wreg[58 + j] = (double)Wih1[(lane + 64) * HID + j];
        }
        b0A = (double)bih0[lane]      + (double)bhh0[lane];
        b0B = (double)bih0[lane + 64] + (double)bhh0[lane + 64];
        b1A = (double)bih1[lane]      + (double)bhh1[lane];
        b1B = (double)bih1[lane + 64] + (double)bhh1[lane + 64];
    }

    // x prefetch (role 2, lanes 0..51): lane = e*13 + i, one float per step
    const float* xptr = nullptr;
    float xUse = 0.f, xFly = 0.f;
    if (role == 2 && lane < IN * EPB) {
        int xe = lane / IN, xi = lane - xe * IN;
        xptr = X + (size_t)(eA + xe) * (T_STEPS * IN) + xi;
    }

    // loop-carried state
    double cst0 = 0.0, cst1 = 0.0;     // cells (role0/1: one; role3: two)
    double hown0 = 0.0, hown1 = 0.0;   // h owned by this lane (readlane sources)

    // ---- prologue: P_x[0] ----
    if (role == 2) {
        float x0 = 0.f;
        if (xptr) { x0 = xptr[0]; xUse = xptr[IN]; xFly = xptr[2 * IN]; }
        double pA[EPB], pB[EPB];
        #pragma unroll
        for (int e = 0; e < EPB; ++e) { pA[e] = b0A; pB[e] = b0B; }
        #pragma unroll
        for (int i = 0; i < IN; ++i) {
            #pragma unroll
            for (int e = 0; e < EPB; ++e) {
                int xb = __builtin_amdgcn_readlane(__float_as_int(x0), e * IN + i);
                double xd = (double)__int_as_float(xb);
                pA[e] = fma(wreg[i],      xd, pA[e]);
                pB[e] = fma(wreg[13 + i], xd, pB[e]);
            }
        }
        #pragma unroll
        for (int e = 0; e < EPB; ++e) { Px[0][lane][e] = pA[e]; Px[0][lane][4 + e] = pB[e]; }
    }
    __syncthreads();

    #pragma unroll 1
    for (int k = 0; k <= T_STEPS + 1; ++k) {
        if (role <= 1) {
            // ---- L0 recurrence: h0[k] for elems {2*role, 2*role+1} ----
            if (k < T_STEPS) {
                const int eoff = role * 2;
                const double* px = &Px[k & 1][lane][0];
                double a0 = px[eoff], a1 = px[eoff + 1];       // row `lane`  (i|f)
                double b0 = px[4 + eoff], b1 = px[5 + eoff];   // row lane+64 (g|o)
                #pragma unroll
                for (int j = 0; j < HID; ++j) {
                    double hj0 = bcast_d(hown0, j);        // h0[j][eoff]
                    double hj1 = bcast_d(hown0, 32 + j);   // h0[j][eoff+1]
                    a0 = fma(wreg[j],      hj0, a0); a1 = fma(wreg[j],      hj1, a1);
                    b0 = fma(wreg[32 + j], hj0, b0); b1 = fma(wreg[32 + j], hj1, b1);
                }
                double sA0 = sigmoid_d(a0), sA1 = sigmoid_d(a1);   // i|f: always sigmoid
                bool ist = !hi32;                                   // row lane+64: g (tanh) | o
                double sB0 = act_fn(b0, ist), sB1 = act_fn(b1, ist);
                double tA0 = shflx32_d(sA0), tA1 = shflx32_d(sA1);
                double tB0 = shflx32_d(sB0), tB1 = shflx32_d(sB1);
                double i_ = hi32 ? tA1 : sA0;
                double f_ = hi32 ? sA1 : tA0;
                double g_ = hi32 ? tB1 : sB0;
                double o_ = hi32 ? sB1 : tB0;
                cst0  = fma(f_, cst0, i_ * g_);
                hown0 = o_ * tanh_d(cst0);
                h0L[k & 1][eoff + (hi32 ? 1 : 0)][l32] = hown0;
            }
        } else if (role == 2) {
            // ---- feeder: P_x[k+1] (t<=999) ----
            if (k <= T_STEPS - 2) {
                float xc = xUse;
                double pA[EPB], pB[EPB];
                #pragma unroll
                for (int e = 0; e < EPB; ++e) { pA[e] = b0A; pB[e] = b0B; }
                #pragma unroll
                for (int i = 0; i < IN; ++i) {
                    #pragma unroll
                    for (int e = 0; e < EPB; ++e) {
                        int xb = __builtin_amdgcn_readlane(__float_as_int(xc), e * IN + i);
                        double xd = (double)__int_as_float(xb);
                        pA[e] = fma(wreg[i],      xd, pA[e]);
                        pB[e] = fma(wreg[13 + i], xd, pB[e]);
                    }
                }
                const int wp = (k + 1) & 1;
                #pragma unroll
                for (int e = 0; e < EPB; ++e) { Px[wp][lane][e] = pA[e]; Px[wp][lane][4 + e] = pB[e]; }
                xUse = xFly;
                if (xptr && (k + 3 <= T_STEPS - 1)) xFly = xptr[(k + 3) * IN];
            }
            // ---- feeder: P_ih for L1 step s=k-1 (uses h0[k-1]) ----
            if (k >= 1 && k <= T_STEPS) {
                const int par = (k - 1) & 1;
                double hs0 = h0L[par][lane >> 5][l32];        // elems 0/1 source
                double hs1 = h0L[par][2 + (lane >> 5)][l32];  // elems 2/3 source
                double qA[EPB], qB[EPB];
                #pragma unroll
                for (int e = 0; e < EPB; ++e) { qA[e] = b1A; qB[e] = b1B; }
                #pragma unroll
                for (int j = 0; j < HID; ++j) {
                    double h0j0 = bcast_d(hs0, j);
                    double h0j1 = bcast_d(hs0, 32 + j);
                    double h0j2 = bcast_d(hs1, j);
                    double h0j3 = bcast_d(hs1, 32 + j);
                    qA[0] = fma(wreg[26 + j], h0j0, qA[0]); qB[0] = fma(wreg[58 + j], h0j0, qB[0]);
                    qA[1] = fma(wreg[26 + j], h0j1, qA[1]); qB[1] = fma(wreg[58 + j], h0j1, qB[1]);
                    qA[2] = fma(wreg[26 + j], h0j2, qA[2]); qB[2] = fma(wreg[58 + j], h0j2, qB[2]);
                    qA[3] = fma(wreg[26 + j], h0j3, qA[3]); qB[3] = fma(wreg[58 + j], h0j3, qB[3]);
                }
                #pragma unroll
                for (int e = 0; e < EPB; ++e) { Pi[par][lane][e] = qA[e]; Pi[par][lane][4 + e] = qB[e]; }
            }
        } else {
            // ---- L1 recurrence: finish step s=k-2 (gates = Pi(s) + Whh1*h1[s-1]) ----
            if (k >= 2) {
                const int par = k & 1;   // (k-2)&1 == k&1
                const double* pi = &Pi[par][lane][0];
                double a[EPB] = { pi[0], pi[1], pi[2], pi[3] };
                double b[EPB] = { pi[4], pi[5], pi[6], pi[7] };
                #pragma unroll
                for (int j = 0; j < HID; ++j) {
                    double h10 = bcast_d(hown0, j);
                    double h11 = bcast_d(hown1, j);
                    double h12 = bcast_d(hown0, 32 + j);
                    double h13 = bcast_d(hown1, 32 + j);
                    a[0] = fma(wreg[j], h10, a[0]); b[0] = fma(wreg[32 + j], h10, b[0]);
                    a[1] = fma(wreg[j], h11, a[1]); b[1] = fma(wreg[32 + j], h11, b[1]);
                    a[2] = fma(wreg[j], h12, a[2]); b[2] = fma(wreg[32 + j], h12, b[2]);
                    a[3] = fma(wreg[j], h13, a[3]); b[3] = fma(wreg[32 + j], h13, b[3]);
                }
                bool ist = !hi32;
                double sA[EPB], sB[EPB], tA[EPB], tB[EPB];
                #pragma unroll
                for (int e = 0; e < EPB; ++e) { sA[e] = sigmoid_d(a[e]); sB[e] = act_fn(b[e], ist); }
                #pragma unroll
                for (int e = 0; e < EPB; ++e) { tA[e] = shflx32_d(sA[e]); tB[e] = shflx32_d(sB[e]); }
                // lane<32: cells (u,e0),(u,e1); lane>=32: cells (u,e2),(u,e3)
                double i0 = hi32 ? tA[2] : sA[0];
                double f0 = hi32 ? sA[2] : tA[0];
                double g0 = hi32 ? tB[2] : sB[0];
                double o0 = hi32 ? sB[2] : tB[0];
                double i1 = hi32 ? tA[3] : sA[1];
                double f1 = hi32 ? sA[3] : tA[1];
                double g1 = hi32 ? tB[3] : sB[1];
                double o1 = hi32 ? sB[3] : tB[1];
                cst0  = fma(f0, cst0, i0 * g0);
                hown0 = o0 * tanh_d(cst0);
                cst1  = fma(f1, cst1, i1 * g1);
                hown1 = o1 * tanh_d(cst1);
            }
        }
        __syncthreads();
    }

    // ---- publish final h1, then classifier head in f64 (identical to R3/R5) ----
    if (role == 3) {
        h1F[hi32 ? 2 : 0][l32] = hown0;
        h1F[hi32 ? 3 : 1][l32] = hown1;
    }
    __syncthreads();
    if (tid < 128) {
        const int e = tid >> 5, j = tid & 31;
        double acc = (double)bc1[j];
        #pragma unroll
        for (int jj = 0; jj < HID; ++jj)
            acc = fma((double)Wc1[j * HID + jj], h1F[e][jj], acc);
        hidb[j][e] = fmax(acc, 0.0);
    }
    __syncthreads();
    if (tid < 3 * EPB) {
        const int e = tid / 3, c = tid % 3;
        double v = (double)bc2[c];
        #pragma unroll
        for (int j = 0; j < HID; ++j)
            v = fma((double)Wc2[c * HID + j], hidb[j][e], v);
        out[(eA + e) * 3 + c] = (float)v;
    }
}

extern "C" void kernel_launch(void* const* d_in, const int* in_sizes, int n_in,
                              void* d_out, int out_size, void* d_ws, size_t ws_size,
                              hipStream_t stream) {
    const float* X    = (const float*)d_in[0];
    const float* Wih0 = (const float*)d_in[1];
    const float* Whh0 = (const float*)d_in[2];
    const float* bih0 = (const float*)d_in[3];
    const float* bhh0 = (const float*)d_in[4];
    const float* Wih1 = (const float*)d_in[5];
    const float* Whh1 = (const float*)d_in[6];
    const float* bih1 = (const float*)d_in[7];
    const float* bhh1 = (const float*)d_in[8];
    const float* Wc1  = (const float*)d_in[9];
    const float* bc1  = (const float*)d_in[10];
    const float* Wc2  = (const float*)d_in[11];
    const float* bc2  = (const float*)d_in[12];

    lstm_fused<<<512, 256, 0, stream>>>(X, Wih0, Whh0, bih0, bhh0,
                                        Wih1, Whh1, bih1, bhh1,
                                        Wc1, bc1, Wc2, bc2, (float*)d_out);
}